// Round 11
// baseline (235.915 us; speedup 1.0000x reference)
//
#include <hip/hip_runtime.h>
#include <hip/hip_bf16.h>
#include <math.h>

#define N_NODES 4096
#define F_INN   256
#define F_OUTT  64
#define HID     64
#define MAXDEG  64

typedef __attribute__((ext_vector_type(8))) short bf16x8;
typedef __attribute__((ext_vector_type(4))) float f32x4;

// Scratch in device globals (no ws_size dependence). Fully rewritten each call.
__device__ int    g_mode;                    // 0 = fp32 inputs, 1 = bf16 inputs
__device__ int    g_anyArr[64];              // per-block detector flags
__device__ float  g_Wh [N_NODES * F_OUTT];
__device__ float  g_s1 [N_NODES];
__device__ float  g_s2 [N_NODES];
__device__ int    g_rev[N_NODES * MAXDEG];
__device__ int    g_perm[N_NODES];
__device__ int    g_nbr[N_NODES * MAXDEG];   // ordered neighbor lists (j ascending)
__device__ int    g_cnt[N_NODES];            // neighbor counts
__device__ float  g_WihT[64 * 256];          // r19: transposed fp32 w_ih
__device__ float  g_bias[256];               // fp32 b_ih + b_hh (r17)
__device__ float4 g_GX [N_NODES * F_OUTT];   // per (node, unit): quad {i,f,g,o} + bias

__device__ __forceinline__ float bf2f(unsigned short u) {
  union { unsigned int i; float f; } v; v.i = ((unsigned int)u) << 16; return v.f;
}
__device__ __forceinline__ unsigned short f2bf(float f) {   // RNE
  union { __hip_bfloat16 b; unsigned short u; } v; v.b = __float2bfloat16(f); return v.u;
}

__device__ __forceinline__ float bcastf(float v, int l) {
  return __int_as_float(__builtin_amdgcn_readlane(__float_as_int(v), l));
}

// r13: raw v_rcp_f32 (proven: 245 -> 227us).
__device__ __forceinline__ float rcp_fast(float x) { return __builtin_amdgcn_rcpf(x); }

__device__ __forceinline__ float sigm(float x) {
  return rcp_fast(1.f + __expf(-x));                   // mul,exp,add,rcp
}
__device__ __forceinline__ float tanh_fast(float x) {
  return fmaf(-2.f, rcp_fast(1.f + __expf(2.f * x)), 1.f);  // mul,exp,add,rcp,fma
}

// count of set bits in mask among lanes strictly below mine
__device__ __forceinline__ int mbcnt64(unsigned long long m) {
  return __builtin_amdgcn_mbcnt_hi((unsigned)(m >> 32),
         __builtin_amdgcn_mbcnt_lo((unsigned)(m & 0xFFFFFFFFull), 0));
}

__device__ __forceinline__ bf16x8 zfrag() {
  bf16x8 z;
  #pragma unroll
  for (int i = 0; i < 8; i++) z[i] = 0;
  return z;
}

#define MFMA16(a, b, c) __builtin_amdgcn_mfma_f32_16x16x32_bf16((a), (b), (c), 0, 0, 0)

// D0: parallel dtype detector (fp32 adj words have zero low16; bf16 doesn't).
__global__ __launch_bounds__(256) void k_detect(const unsigned int* __restrict__ aw) {
  __shared__ int any;
  if (threadIdx.x == 0) any = 0;
  __syncthreads();
  const uint4 v = ((const uint4*)aw)[blockIdx.x * 256 + threadIdx.x];
  int loc = (int)((v.x & 0xFFFFu) | (v.y & 0xFFFFu) | (v.z & 0xFFFFu) | (v.w & 0xFFFFu));
  if (loc) atomicOr(&any, 1);
  __syncthreads();
  if (threadIdx.x == 0) g_anyArr[blockIdx.x] = any;
}

// S1: reduce detector flags -> g_mode; counting sort by seq_length descending.
__global__ __launch_bounds__(256) void k_sort(const int* __restrict__ seq) {
  __shared__ int hist[MAXDEG + 1];
  __shared__ int offs[MAXDEG + 1];
  const int tid = threadIdx.x;
  if (tid <= MAXDEG) hist[tid] = 0;
  __syncthreads();
  if (tid == 0) {
    int any = 0;
    for (int b = 0; b < 64; b++) any |= g_anyArr[b];
    g_mode = any ? 1 : 0;
  }
  for (int i = tid; i < N_NODES; i += 256)
    atomicAdd(&hist[min(max(seq[i], 0), MAXDEG)], 1);
  __syncthreads();
  if (tid == 0) {
    int run = 0;
    for (int L = MAXDEG; L >= 0; L--) { offs[L] = run; run += hist[L]; }
  }
  __syncthreads();
  for (int i = tid; i < N_NODES; i += 256) {
    int p = atomicAdd(&offs[min(max(seq[i], 0), MAXDEG)], 1);
    g_perm[p] = i;
  }
}

// K-SCAN (r15): block-per-row adj streaming + ordered neighbor extraction.
// r19: blocks 0..63 fill g_WihT; block 64 fills g_bias.
__global__ __launch_bounds__(256) void k_scan(
    const void* __restrict__ adj, const void* __restrict__ w_ih,
    const void* __restrict__ b_ih, const void* __restrict__ b_hh)
{
  const bool bf16 = (g_mode == 1);
  const int i = blockIdx.x;
  const int w = threadIdx.x >> 6, lane = threadIdx.x & 63;
  __shared__ int seg[4][MAXDEG];
  __shared__ int scnt[4];

  if (i < 64) {
    const int unit = threadIdx.x >> 2, g = threadIdx.x & 3;
    const int src = (g * 64 + unit) * F_OUTT + i;       // w_ih[gate*64+unit][f]
    g_WihT[i * 256 + threadIdx.x] =
        bf16 ? bf2f(((const unsigned short*)w_ih)[src]) : ((const float*)w_ih)[src];
  } else if (i == 64) {
    const int t = threadIdx.x;                    // 0..255
    g_bias[t] = bf16 ? (bf2f(((const unsigned short*)b_ih)[t]) +
                        bf2f(((const unsigned short*)b_hh)[t]))
                     : (((const float*)b_ih)[t] + ((const float*)b_hh)[t]);
  }

  int base = 0;
  if (bf16) {
    const uint4* ar = (const uint4*)((const unsigned short*)adj + (size_t)i * N_NODES);
    #pragma unroll
    for (int it = 0; it < 2; it++) {
      const uint4 v = ar[w * 128 + it * 64 + lane];
      unsigned word[4] = {v.x, v.y, v.z, v.w};
      bool nz[8];
      #pragma unroll
      for (int k = 0; k < 4; k++) {
        nz[2 * k]     = (word[k] & 0x0000FFFFu) != 0u;
        nz[2 * k + 1] = (word[k] & 0xFFFF0000u) != 0u;
      }
      int pre = 0, tot = 0;
      #pragma unroll
      for (int k = 0; k < 8; k++) {
        unsigned long long bl = __ballot(nz[k]);
        pre += mbcnt64(bl);
        tot += __popcll(bl);
      }
      int loc = 0;
      #pragma unroll
      for (int k = 0; k < 8; k++) {
        if (nz[k]) {
          int p = base + pre + loc;
          if (p < MAXDEG) seg[w][p] = w * 1024 + it * 512 + lane * 8 + k;
          loc++;
        }
      }
      base += tot;
    }
  } else {
    const float4* ar = (const float4*)((const float*)adj + (size_t)i * N_NODES);
    #pragma unroll
    for (int it = 0; it < 4; it++) {
      const float4 v = ar[w * 256 + it * 64 + lane];
      bool nz[4] = {v.x != 0.0f, v.y != 0.0f, v.z != 0.0f, v.w != 0.0f};
      int pre = 0, tot = 0;
      #pragma unroll
      for (int k = 0; k < 4; k++) {
        unsigned long long bl = __ballot(nz[k]);
        pre += mbcnt64(bl);
        tot += __popcll(bl);
      }
      int loc = 0;
      #pragma unroll
      for (int k = 0; k < 4; k++) {
        if (nz[k]) {
          int p = base + pre + loc;
          if (p < MAXDEG) seg[w][p] = w * 1024 + it * 256 + lane * 4 + k;
          loc++;
        }
      }
      base += tot;
    }
  }
  if (lane == 0) scnt[w] = base;
  __syncthreads();
  int off = 0;
  #pragma unroll
  for (int u = 0; u < 4; u++) off += (u < w) ? scnt[u] : 0;
  const int cw = min(scnt[w], MAXDEG);
  if (lane < cw) {
    const int p = off + lane;
    if (p < MAXDEG) g_nbr[i * MAXDEG + p] = seg[w][lane];
  }
  if (threadIdx.x == 0)
    g_cnt[i] = min(scnt[0] + scnt[1] + scnt[2] + scnt[3], MAXDEG);
}

// K1 v2 (r17): Wh = h @ W, 4 rows per wave. Unchanged (bit-identical fp64).
__global__ __launch_bounds__(256) void k_wh(
    const void* __restrict__ h, const void* __restrict__ W, const void* __restrict__ a)
{
  const bool bf16 = (g_mode == 1);
  __shared__ float Ws[F_INN * F_OUTT];   // 64 KB
  const int tid = threadIdx.x;
  if (bf16) {
    const ushort4* Wu = (const ushort4*)W;
    for (int v = tid; v < F_INN * F_OUTT / 4; v += 256) {
      ushort4 u = Wu[v];
      ((float4*)Ws)[v] = make_float4(bf2f(u.x), bf2f(u.y), bf2f(u.z), bf2f(u.w));
    }
  } else {
    const float4* Wf = (const float4*)W;
    for (int v = tid; v < F_INN * F_OUTT / 4; v += 256) ((float4*)Ws)[v] = Wf[v];
  }
  __syncthreads();
  const int wave = tid >> 6, lane = tid & 63;
  const int row0 = blockIdx.x * 16 + wave * 4;

  float hr[4][4];
  #pragma unroll
  for (int r = 0; r < 4; r++) {
    if (bf16) {
      ushort4 v = ((const ushort4*)((const unsigned short*)h + (row0 + r) * F_INN))[lane];
      hr[0][r] = bf2f(v.x); hr[1][r] = bf2f(v.y); hr[2][r] = bf2f(v.z); hr[3][r] = bf2f(v.w);
    } else {
      float4 v = ((const float4*)((const float*)h + (row0 + r) * F_INN))[lane];
      hr[0][r] = v.x; hr[1][r] = v.y; hr[2][r] = v.z; hr[3][r] = v.w;
    }
  }

  double acc[4] = {0.0, 0.0, 0.0, 0.0};
  #pragma unroll 4
  for (int l = 0; l < 64; l++) {
    #pragma unroll
    for (int j = 0; j < 4; j++) {
      const double wd = (double)Ws[(l * 4 + j) * F_OUTT + lane];
      #pragma unroll
      for (int r = 0; r < 4; r++)
        acc[r] += (double)bcastf(hr[j][r], l) * wd;
    }
  }

  float a1, a2;
  if (bf16) {
    a1 = bf2f(((const unsigned short*)a)[lane]);
    a2 = bf2f(((const unsigned short*)a)[F_OUTT + lane]);
  } else {
    a1 = ((const float*)a)[lane];
    a2 = ((const float*)a)[F_OUTT + lane];
  }

  #pragma unroll
  for (int r = 0; r < 4; r++) {
    const float whv = (float)acc[r];
    g_Wh[(row0 + r) * F_OUTT + lane] = whv;
    double t1 = (double)whv * (double)a1;
    double t2 = (double)whv * (double)a2;
    #pragma unroll
    for (int off = 32; off > 0; off >>= 1) {
      t1 += __shfl_down(t1, off);
      t2 += __shfl_down(t2, off);
    }
    if (lane == 0) { g_s1[row0 + r] = (float)t1; g_s2[row0 + r] = (float)t2; }
  }
}

// K2 v6 (r19-proven): coalesced-GEMV tail. Unchanged.
__global__ __launch_bounds__(64) void k_att2(void) {
  const int lane = threadIdx.x & 63;
  const int i = blockIdx.x;

  __shared__ int srt[MAXDEG];

  const int L = __builtin_amdgcn_readfirstlane(min(g_cnt[i], MAXDEG));
  int jn = 0;
  if (lane < L) jn = g_nbr[i * MAXDEG + lane] & (N_NODES - 1);

  const float s2v = g_s2[jn];
  float av;
  {
    float s = g_s1[i] + s2v;
    float e = (s > 0.0f) ? s : 0.2f * s;
    if (lane >= L) e = -3.0e38f;
    float m = e;
    #pragma unroll
    for (int off = 32; off > 0; off >>= 1) m = fmaxf(m, __shfl_xor(m, off));
    float p = (lane < L) ? __expf(e - m) : 0.0f;
    float ssum = p;
    #pragma unroll
    for (int off = 32; off > 0; off >>= 1) ssum += __shfl_xor(ssum, off);
    av = p * rcp_fast(ssum);
    int rank = 0;
    for (int qq = 0; qq < L; qq++) {
      const float aq = bcastf(av, qq);                        // v_readlane
      const int   jq = __builtin_amdgcn_readlane(jn, qq);     // v_readlane
      rank += (aq > av || (aq == av && jq < jn)) ? 1 : 0;
    }
    if (lane < L) srt[rank] = jn;
  }
  g_rev[i * MAXDEG + lane] = (lane < L) ? srt[L - 1 - lane] : 0;

  float a0 = 0.f, a1 = 0.f, a2 = 0.f, a3 = 0.f;
  float a4 = 0.f, a5 = 0.f, a6 = 0.f, a7 = 0.f;
  int q = 0;
  for (; q + 8 <= L; q += 8) {
    a0 = fmaf(bcastf(av, q    ), g_Wh[(size_t)__builtin_amdgcn_readlane(jn, q    ) * F_OUTT + lane], a0);
    a1 = fmaf(bcastf(av, q + 1), g_Wh[(size_t)__builtin_amdgcn_readlane(jn, q + 1) * F_OUTT + lane], a1);
    a2 = fmaf(bcastf(av, q + 2), g_Wh[(size_t)__builtin_amdgcn_readlane(jn, q + 2) * F_OUTT + lane], a2);
    a3 = fmaf(bcastf(av, q + 3), g_Wh[(size_t)__builtin_amdgcn_readlane(jn, q + 3) * F_OUTT + lane], a3);
    a4 = fmaf(bcastf(av, q + 4), g_Wh[(size_t)__builtin_amdgcn_readlane(jn, q + 4) * F_OUTT + lane], a4);
    a5 = fmaf(bcastf(av, q + 5), g_Wh[(size_t)__builtin_amdgcn_readlane(jn, q + 5) * F_OUTT + lane], a5);
    a6 = fmaf(bcastf(av, q + 6), g_Wh[(size_t)__builtin_amdgcn_readlane(jn, q + 6) * F_OUTT + lane], a6);
    a7 = fmaf(bcastf(av, q + 7), g_Wh[(size_t)__builtin_amdgcn_readlane(jn, q + 7) * F_OUTT + lane], a7);
  }
  for (; q < L; q++)
    a0 = fmaf(bcastf(av, q), g_Wh[(size_t)__builtin_amdgcn_readlane(jn, q) * F_OUTT + lane], a0);
  const float wh2v = ((a0 + a1) + (a2 + a3)) + ((a4 + a5) + (a6 + a7));

  float gx0 = 0.f, gx1 = 0.f, gx2 = 0.f, gx3 = 0.f;
  #pragma unroll
  for (int f = 0; f < 64; f++) {
    const float wf = bcastf(wh2v, f);
    const float4 cv = *(const float4*)(g_WihT + f * 256 + lane * 4);
    gx0 = fmaf(cv.x, wf, gx0);
    gx1 = fmaf(cv.y, wf, gx1);
    gx2 = fmaf(cv.z, wf, gx2);
    gx3 = fmaf(cv.w, wf, gx3);
  }
  gx0 += g_bias[0 * 64 + lane];
  gx1 += g_bias[1 * 64 + lane];
  gx2 += g_bias[2 * 64 + lane];
  gx3 += g_bias[3 * 64 + lane];
  g_GX[(size_t)i * F_OUTT + lane] = make_float4(gx0, gx1, gx2, gx3);
}

// K4-MFMA v13 (r21, resubmit r22 — r10 bench was an infra failure, kernel
// audited memory-safe / hang-free): wave-private recurrence, ZERO barriers.
// r9 post-mortem: pairing remap was null -> wall = Lmax block's 64-step
// chain (~1920cy/step); bounded components sum to ~1000cy, so the residual
// ~900cy is inter-wave coupling (4-wave s_barrier skew + cross-wave LDS/
// bpermute serialization at 8 waves/CU). v13 removes ALL of it:
// - 1 wave = 4 rows (1024 blocks x 64 thr, ~1 wave/SIMD). The wave computes
//   all 256 gate cols itself: 16 N-tiles x 2 K-chained MFMAs (M=16, 4 live
//   rows), C=0; gx added lane-locally after redistribution (fp32 reorder
//   ~1e-6, well under budget).
// - D->cell redistribution via SAME-WAVE LDS (16 predicated b128 writes +
//   4 b128 reads); same-wave DS ops execute in order (r2-proven) -> no
//   s_barrier anywhere in the kernel.
// - B cols chosen as gate*64+unit so lane l reads exactly unit l's gate
//   quads: tile n=4g+q, col c -> w_hh row 64g+16q+c = 64g+lane.
// - h stays in wave-private LDS (rows 4..15 zeroed once -> phantom A rows
//   are 0); proven depth-4 gx ring kept (snapshot slot before reload).
// Known risk to check in counters: VGPR (~240 est) — if spilling, B[] goes
// back to LDS next round.
__global__ __launch_bounds__(64, 1) void k_lstm_mfma(
    const void* __restrict__ w_hh, const int* __restrict__ seq,
    void* __restrict__ out)
{
  const bool bf16 = (g_mode == 1);
  __shared__ __align__(16) unsigned short lds_h[16 * 72];  // 2.25 KB; rows 4..15 stay 0
  __shared__ __align__(16) float lds_g[16 * 16 * 4];       // 4 KB: [tile][c][reg]
  __shared__ int lds_idx[4][MAXDEG];                       // 1 KB rev indices
  const int lane = threadIdx.x & 63;
  const int q = lane >> 4, c = lane & 15;
  const int rb = blockIdx.x * 4;

  // Zero lds_h once (rows 4..15 = phantom A rows must read 0 forever).
  for (int v = lane; v < 16 * 72; v += 64) lds_h[v] = 0;

  // Stage this wave's 4 rev-index rows (coalesced; same-wave use below).
  for (int v = lane; v < 4 * MAXDEG; v += 64) {
    const int e = v >> 6, t0 = v & (MAXDEG - 1);
    const int row = g_perm[rb + e] & (N_NODES - 1);
    lds_idx[e][t0] = g_rev[row * MAXDEG + t0] & (N_NODES - 1);
  }

  int row_own[4], Ls_own[4];
  #pragma unroll
  for (int r = 0; r < 4; r++) {
    row_own[r] = g_perm[rb + r] & (N_NODES - 1);
    Ls_own[r]  = min(max(seq[row_own[r]], 0), MAXDEG);
  }
  const int Lmax = max(max(Ls_own[0], Ls_own[1]), max(Ls_own[2], Ls_own[3]));

  // B fragments: tile n covers w_hh rows (gate cols) 16n..16n+15.
  // frag(n,ch) at lane (q,c): col 16n+c, k = 32ch + 8q + e.
  bf16x8 B[16][2];
  #pragma unroll
  for (int n = 0; n < 16; n++) {
    #pragma unroll
    for (int ch = 0; ch < 2; ch++) {
      if (bf16) {
        B[n][ch] = *(const bf16x8*)((const unsigned short*)w_hh +
                                    (size_t)(16 * n + c) * 64 + ch * 32 + q * 8);
      } else {
        const float* wp = (const float*)w_hh + (size_t)(16 * n + c) * 64 + ch * 32 + q * 8;
        float4 va = *(const float4*)wp, vb = *(const float4*)(wp + 4);
        bf16x8 f;
        f[0] = (short)f2bf(va.x); f[1] = (short)f2bf(va.y);
        f[2] = (short)f2bf(va.z); f[3] = (short)f2bf(va.w);
        f[4] = (short)f2bf(vb.x); f[5] = (short)f2bf(vb.y);
        f[6] = (short)f2bf(vb.z); f[7] = (short)f2bf(vb.w);
        B[n][ch] = f;
      }
    }
  }

  // Depth-4 gx register ring: unit = lane, rows 0..3 of this wave.
  float4 gxb[4][4];
  #pragma unroll
  for (int s = 0; s < 4; s++) {
    #pragma unroll
    for (int r = 0; r < 4; r++)
      gxb[s][r] = g_GX[lds_idx[r][s] * F_OUTT + lane];
  }
  int idx_cur[4];
  #pragma unroll
  for (int r = 0; r < 4; r++) idx_cur[r] = lds_idx[r][4];

  f32x4 zc;
  zc[0] = 0.f; zc[1] = 0.f; zc[2] = 0.f; zc[3] = 0.f;

  bf16x8 h0 = zfrag(), h1 = zfrag();
  float cst[4] = {0.f, 0.f, 0.f, 0.f}, hst[4] = {0.f, 0.f, 0.f, 0.f};
  const int Lr = (Lmax + 3) & ~3;   // dead tail sub-steps are live-masked

  for (int t = 0; t < Lr; t += 4) {
    #pragma unroll
    for (int j = 0; j < 4; j++) {
      const int tt = t + j;
      // 1. 32 MFMAs (16 indep 2-chains), C=0; q==0 lanes stash D rows 0..3.
      #pragma unroll
      for (int n = 0; n < 16; n++) {
        f32x4 a = MFMA16(h0, B[n][0], zc);
        a = MFMA16(h1, B[n][1], a);
        if (q == 0) *((f32x4*)(lds_g + (n * 16 + c) * 4)) = a;
      }
      // 2. snapshot ring slot j, then reload it with step tt+4 data.
      float4 gxt[4];
      #pragma unroll
      for (int r = 0; r < 4; r++) gxt[r] = gxb[j][r];
      #pragma unroll
      for (int r = 0; r < 4; r++)
        gxb[j][r] = g_GX[idx_cur[r] * F_OUTT + lane];
      {
        const int nt = min(tt + 5, MAXDEG - 1);
        #pragma unroll
        for (int r = 0; r < 4; r++) idx_cur[r] = lds_idx[r][nt];
      }
      // 3. gather my unit's gate quads (tile 4g+q, col c -> unit = lane).
      //    Same-wave DS ordering guarantees the writes above are visible.
      f32x4 gv[4];
      #pragma unroll
      for (int g = 0; g < 4; g++)
        gv[g] = *((const f32x4*)(lds_g + ((g * 4 + q) * 16 + c) * 4));
      // 4. cells: rows 0..3 at unit=lane; gx added here (was MFMA C-in).
      #pragma unroll
      for (int r = 0; r < 4; r++) {
        float ig = sigm(gv[0][r] + gxt[r].x);
        float fg = sigm(gv[1][r] + gxt[r].y);
        float gg = tanh_fast(gv[2][r] + gxt[r].z);
        float og = sigm(gv[3][r] + gxt[r].w);
        float cn = fg * cst[r] + ig * gg;
        float hn = og * tanh_fast(cn);
        bool live = (tt < Ls_own[r]);
        cst[r] = live ? cn : cst[r];
        hst[r] = live ? hn : hst[r];
        lds_h[r * 72 + lane] = f2bf(hst[r]);   // RNE bf16
      }
      // 5. next A fragments: row m=c (rows 4..15 zero), k = 32ch + 8q + e.
      {
        const unsigned short* lr_ = lds_h + c * 72;
        h0 = *(const bf16x8*)(lr_ + 8 * q);
        h1 = *(const bf16x8*)(lr_ + 32 + 8 * q);
      }
    }
  }
  #pragma unroll
  for (int r = 0; r < 4; r++) {
    if (bf16) ((__hip_bfloat16*)out)[row_own[r] * HID + lane] = __float2bfloat16(hst[r]);
    else      ((float*)out)[row_own[r] * HID + lane] = hst[r];
  }
}

extern "C" void kernel_launch(void* const* d_in, const int* in_sizes, int n_in,
                              void* d_out, int out_size, void* d_ws, size_t ws_size,
                              hipStream_t stream) {
  (void)in_sizes; (void)n_in; (void)out_size; (void)d_ws; (void)ws_size;
  const void* h    = d_in[0];
  const void* adj  = d_in[1];
  const int*  seq  = (const int*)d_in[2];
  const void* W    = d_in[3];
  const void* a    = d_in[4];
  const void* w_ih = d_in[5];
  const void* w_hh = d_in[6];
  const void* b_ih = d_in[7];
  const void* b_hh = d_in[8];

  k_detect   <<<64,           256, 0, stream>>>((const unsigned int*)adj);
  k_sort     <<<1,            256, 0, stream>>>(seq);
  k_scan     <<<N_NODES,      256, 0, stream>>>(adj, w_ih, b_ih, b_hh);
  k_wh       <<<N_NODES / 16, 256, 0, stream>>>(h, W, a);
  k_att2     <<<N_NODES,      64,  0, stream>>>();
  k_lstm_mfma<<<N_NODES / 4,  64,  0, stream>>>(w_hh, seq, d_out);
}

// Round 12
// 197.094 us; speedup vs baseline: 1.1970x; 1.1970x over previous
//
#include <hip/hip_runtime.h>
#include <hip/hip_bf16.h>
#include <math.h>

#define N_NODES 4096
#define F_INN   256
#define F_OUTT  64
#define HID     64
#define MAXDEG  64

typedef __attribute__((ext_vector_type(8))) short bf16x8;
typedef __attribute__((ext_vector_type(4))) float f32x4;

// Scratch in device globals (no ws_size dependence). Fully rewritten each call.
__device__ int    g_anyArr[64];              // per-block detector flags
__device__ float  g_Wh [N_NODES * F_OUTT];
__device__ float  g_s1 [N_NODES];
__device__ float  g_s2 [N_NODES];
__device__ int    g_rev[N_NODES * MAXDEG];
__device__ int    g_perm[N_NODES];
__device__ int    g_nbr[N_NODES * MAXDEG];   // ordered neighbor lists (j ascending)
__device__ int    g_cnt[N_NODES];            // neighbor counts
__device__ float  g_WihT[64 * 256];          // transposed fp32 w_ih (r19)
__device__ float  g_bias[256];               // fp32 b_ih + b_hh (r17)
__device__ float4 g_GX [N_NODES * F_OUTT];   // per (node, unit): quad {i,f,g,o} + bias

__device__ __forceinline__ float bf2f(unsigned short u) {
  union { unsigned int i; float f; } v; v.i = ((unsigned int)u) << 16; return v.f;
}
__device__ __forceinline__ unsigned short f2bf(float f) {   // RNE
  union { __hip_bfloat16 b; unsigned short u; } v; v.b = __float2bfloat16(f); return v.u;
}

__device__ __forceinline__ float bcastf(float v, int l) {
  return __int_as_float(__builtin_amdgcn_readlane(__float_as_int(v), l));
}

// r13: raw v_rcp_f32 (proven: 245 -> 227us).
__device__ __forceinline__ float rcp_fast(float x) { return __builtin_amdgcn_rcpf(x); }

__device__ __forceinline__ float sigm(float x) {
  return rcp_fast(1.f + __expf(-x));                   // mul,exp,add,rcp
}
__device__ __forceinline__ float tanh_fast(float x) {
  return fmaf(-2.f, rcp_fast(1.f + __expf(2.f * x)), 1.f);  // mul,exp,add,rcp,fma
}

// count of set bits in mask among lanes strictly below mine
__device__ __forceinline__ int mbcnt64(unsigned long long m) {
  return __builtin_amdgcn_mbcnt_hi((unsigned)(m >> 32),
         __builtin_amdgcn_mbcnt_lo((unsigned)(m & 0xFFFFFFFFull), 0));
}

// r24: dtype flag derived per-wave from g_anyArr (64 flags, fully rewritten
// by k_detect each call). 64 L2-hit loads + 1 ballot per wave; every wave in
// every block computes the same answer -> no g_mode global, no serial reduce
// on the launch chain.
__device__ __forceinline__ bool mode_bf16() {
  const int lane = threadIdx.x & 63;
  const int v = g_anyArr[lane];
  return __ballot(v != 0) != 0ull;
}

__device__ __forceinline__ bf16x8 zfrag() {
  bf16x8 z;
  #pragma unroll
  for (int i = 0; i < 8; i++) z[i] = 0;
  return z;
}

// Lightweight block barrier for LDS-only exchange (r10-validated): orders ds
// ops but does not force a vmcnt drain of in-flight global prefetches.
__device__ __forceinline__ void block_sync_lds() {
  __asm__ volatile("s_waitcnt lgkmcnt(0)" ::: "memory");
  __builtin_amdgcn_s_barrier();
}

#define MFMA16(a, b, c) __builtin_amdgcn_mfma_f32_16x16x32_bf16((a), (b), (c), 0, 0, 0)

// D0: parallel dtype detector (fp32 adj words have zero low16; bf16 doesn't).
__global__ __launch_bounds__(256) void k_detect(const unsigned int* __restrict__ aw) {
  __shared__ int any;
  if (threadIdx.x == 0) any = 0;
  __syncthreads();
  const uint4 v = ((const uint4*)aw)[blockIdx.x * 256 + threadIdx.x];
  int loc = (int)((v.x & 0xFFFFu) | (v.y & 0xFFFFu) | (v.z & 0xFFFFu) | (v.w & 0xFFFFu));
  if (loc) atomicOr(&any, 1);
  __syncthreads();
  if (threadIdx.x == 0) g_anyArr[blockIdx.x] = any;
}

// K-SCAN (r24): block-per-row adj streaming + ordered neighbor extraction.
// Blocks 0..63 also fill g_WihT; block 64 fills g_bias; block 4096 runs the
// counting sort (was k_sort) overlapped with the adj stream — one launch
// fewer on the serial chain. Sort block touches only seq/g_perm.
__global__ __launch_bounds__(256) void k_scan(
    const void* __restrict__ adj, const void* __restrict__ w_ih,
    const void* __restrict__ b_ih, const void* __restrict__ b_hh,
    const int* __restrict__ seq)
{
  const int i = blockIdx.x;
  const int tid = threadIdx.x;

  if (i == N_NODES) {   // ---- sort block (old k_sort, mode logic removed)
    __shared__ int hist[MAXDEG + 1];
    __shared__ int offs[MAXDEG + 1];
    if (tid <= MAXDEG) hist[tid] = 0;
    __syncthreads();
    for (int r = tid; r < N_NODES; r += 256)
      atomicAdd(&hist[min(max(seq[r], 0), MAXDEG)], 1);
    __syncthreads();
    if (tid == 0) {
      int run = 0;
      for (int L = MAXDEG; L >= 0; L--) { offs[L] = run; run += hist[L]; }
    }
    __syncthreads();
    for (int r = tid; r < N_NODES; r += 256) {
      int p = atomicAdd(&offs[min(max(seq[r], 0), MAXDEG)], 1);
      g_perm[p] = r;
    }
    return;
  }

  const bool bf16 = mode_bf16();
  const int w = tid >> 6, lane = tid & 63;
  __shared__ int seg[4][MAXDEG];
  __shared__ int scnt[4];

  if (i < 64) {
    const int unit = tid >> 2, g = tid & 3;
    const int src = (g * 64 + unit) * F_OUTT + i;       // w_ih[gate*64+unit][f]
    g_WihT[i * 256 + tid] =
        bf16 ? bf2f(((const unsigned short*)w_ih)[src]) : ((const float*)w_ih)[src];
  } else if (i == 64) {
    g_bias[tid] = bf16 ? (bf2f(((const unsigned short*)b_ih)[tid]) +
                          bf2f(((const unsigned short*)b_hh)[tid]))
                       : (((const float*)b_ih)[tid] + ((const float*)b_hh)[tid]);
  }

  int base = 0;
  if (bf16) {
    const uint4* ar = (const uint4*)((const unsigned short*)adj + (size_t)i * N_NODES);
    #pragma unroll
    for (int it = 0; it < 2; it++) {
      const uint4 v = ar[w * 128 + it * 64 + lane];
      unsigned word[4] = {v.x, v.y, v.z, v.w};
      bool nz[8];
      #pragma unroll
      for (int k = 0; k < 4; k++) {
        nz[2 * k]     = (word[k] & 0x0000FFFFu) != 0u;
        nz[2 * k + 1] = (word[k] & 0xFFFF0000u) != 0u;
      }
      int pre = 0, tot = 0;
      #pragma unroll
      for (int k = 0; k < 8; k++) {
        unsigned long long bl = __ballot(nz[k]);
        pre += mbcnt64(bl);
        tot += __popcll(bl);
      }
      int loc = 0;
      #pragma unroll
      for (int k = 0; k < 8; k++) {
        if (nz[k]) {
          int p = base + pre + loc;
          if (p < MAXDEG) seg[w][p] = w * 1024 + it * 512 + lane * 8 + k;
          loc++;
        }
      }
      base += tot;
    }
  } else {
    const float4* ar = (const float4*)((const float*)adj + (size_t)i * N_NODES);
    #pragma unroll
    for (int it = 0; it < 4; it++) {
      const float4 v = ar[w * 256 + it * 64 + lane];
      bool nz[4] = {v.x != 0.0f, v.y != 0.0f, v.z != 0.0f, v.w != 0.0f};
      int pre = 0, tot = 0;
      #pragma unroll
      for (int k = 0; k < 4; k++) {
        unsigned long long bl = __ballot(nz[k]);
        pre += mbcnt64(bl);
        tot += __popcll(bl);
      }
      int loc = 0;
      #pragma unroll
      for (int k = 0; k < 4; k++) {
        if (nz[k]) {
          int p = base + pre + loc;
          if (p < MAXDEG) seg[w][p] = w * 1024 + it * 256 + lane * 4 + k;
          loc++;
        }
      }
      base += tot;
    }
  }
  if (lane == 0) scnt[w] = base;
  __syncthreads();
  int off = 0;
  #pragma unroll
  for (int u = 0; u < 4; u++) off += (u < w) ? scnt[u] : 0;
  const int cw = min(scnt[w], MAXDEG);
  if (lane < cw) {
    const int p = off + lane;
    if (p < MAXDEG) g_nbr[i * MAXDEG + p] = seg[w][lane];
  }
  if (tid == 0)
    g_cnt[i] = min(scnt[0] + scnt[1] + scnt[2] + scnt[3], MAXDEG);
}

// K1 v2 (r17): Wh = h @ W, 4 rows per wave. Unchanged (bit-identical fp64).
__global__ __launch_bounds__(256) void k_wh(
    const void* __restrict__ h, const void* __restrict__ W, const void* __restrict__ a)
{
  const bool bf16 = mode_bf16();
  __shared__ float Ws[F_INN * F_OUTT];   // 64 KB
  const int tid = threadIdx.x;
  if (bf16) {
    const ushort4* Wu = (const ushort4*)W;
    for (int v = tid; v < F_INN * F_OUTT / 4; v += 256) {
      ushort4 u = Wu[v];
      ((float4*)Ws)[v] = make_float4(bf2f(u.x), bf2f(u.y), bf2f(u.z), bf2f(u.w));
    }
  } else {
    const float4* Wf = (const float4*)W;
    for (int v = tid; v < F_INN * F_OUTT / 4; v += 256) ((float4*)Ws)[v] = Wf[v];
  }
  __syncthreads();
  const int wave = tid >> 6, lane = tid & 63;
  const int row0 = blockIdx.x * 16 + wave * 4;

  float hr[4][4];
  #pragma unroll
  for (int r = 0; r < 4; r++) {
    if (bf16) {
      ushort4 v = ((const ushort4*)((const unsigned short*)h + (row0 + r) * F_INN))[lane];
      hr[0][r] = bf2f(v.x); hr[1][r] = bf2f(v.y); hr[2][r] = bf2f(v.z); hr[3][r] = bf2f(v.w);
    } else {
      float4 v = ((const float4*)((const float*)h + (row0 + r) * F_INN))[lane];
      hr[0][r] = v.x; hr[1][r] = v.y; hr[2][r] = v.z; hr[3][r] = v.w;
    }
  }

  double acc[4] = {0.0, 0.0, 0.0, 0.0};
  #pragma unroll 4
  for (int l = 0; l < 64; l++) {
    #pragma unroll
    for (int j = 0; j < 4; j++) {
      const double wd = (double)Ws[(l * 4 + j) * F_OUTT + lane];
      #pragma unroll
      for (int r = 0; r < 4; r++)
        acc[r] += (double)bcastf(hr[j][r], l) * wd;
    }
  }

  float a1, a2;
  if (bf16) {
    a1 = bf2f(((const unsigned short*)a)[lane]);
    a2 = bf2f(((const unsigned short*)a)[F_OUTT + lane]);
  } else {
    a1 = ((const float*)a)[lane];
    a2 = ((const float*)a)[F_OUTT + lane];
  }

  #pragma unroll
  for (int r = 0; r < 4; r++) {
    const float whv = (float)acc[r];
    g_Wh[(row0 + r) * F_OUTT + lane] = whv;
    double t1 = (double)whv * (double)a1;
    double t2 = (double)whv * (double)a2;
    #pragma unroll
    for (int off = 32; off > 0; off >>= 1) {
      t1 += __shfl_down(t1, off);
      t2 += __shfl_down(t2, off);
    }
    if (lane == 0) { g_s1[row0 + r] = (float)t1; g_s2[row0 + r] = (float)t2; }
  }
}

// K2 v6 (r19-proven): coalesced-GEMV tail. Unchanged (needs no dtype flag).
__global__ __launch_bounds__(64) void k_att2(void) {
  const int lane = threadIdx.x & 63;
  const int i = blockIdx.x;

  __shared__ int srt[MAXDEG];

  const int L = __builtin_amdgcn_readfirstlane(min(g_cnt[i], MAXDEG));
  int jn = 0;
  if (lane < L) jn = g_nbr[i * MAXDEG + lane] & (N_NODES - 1);

  const float s2v = g_s2[jn];
  float av;
  {
    float s = g_s1[i] + s2v;
    float e = (s > 0.0f) ? s : 0.2f * s;
    if (lane >= L) e = -3.0e38f;
    float m = e;
    #pragma unroll
    for (int off = 32; off > 0; off >>= 1) m = fmaxf(m, __shfl_xor(m, off));
    float p = (lane < L) ? __expf(e - m) : 0.0f;
    float ssum = p;
    #pragma unroll
    for (int off = 32; off > 0; off >>= 1) ssum += __shfl_xor(ssum, off);
    av = p * rcp_fast(ssum);
    int rank = 0;
    for (int qq = 0; qq < L; qq++) {
      const float aq = bcastf(av, qq);                        // v_readlane
      const int   jq = __builtin_amdgcn_readlane(jn, qq);     // v_readlane
      rank += (aq > av || (aq == av && jq < jn)) ? 1 : 0;
    }
    if (lane < L) srt[rank] = jn;
  }
  g_rev[i * MAXDEG + lane] = (lane < L) ? srt[L - 1 - lane] : 0;

  float a0 = 0.f, a1 = 0.f, a2 = 0.f, a3 = 0.f;
  float a4 = 0.f, a5 = 0.f, a6 = 0.f, a7 = 0.f;
  int q = 0;
  for (; q + 8 <= L; q += 8) {
    a0 = fmaf(bcastf(av, q    ), g_Wh[(size_t)__builtin_amdgcn_readlane(jn, q    ) * F_OUTT + lane], a0);
    a1 = fmaf(bcastf(av, q + 1), g_Wh[(size_t)__builtin_amdgcn_readlane(jn, q + 1) * F_OUTT + lane], a1);
    a2 = fmaf(bcastf(av, q + 2), g_Wh[(size_t)__builtin_amdgcn_readlane(jn, q + 2) * F_OUTT + lane], a2);
    a3 = fmaf(bcastf(av, q + 3), g_Wh[(size_t)__builtin_amdgcn_readlane(jn, q + 3) * F_OUTT + lane], a3);
    a4 = fmaf(bcastf(av, q + 4), g_Wh[(size_t)__builtin_amdgcn_readlane(jn, q + 4) * F_OUTT + lane], a4);
    a5 = fmaf(bcastf(av, q + 5), g_Wh[(size_t)__builtin_amdgcn_readlane(jn, q + 5) * F_OUTT + lane], a5);
    a6 = fmaf(bcastf(av, q + 6), g_Wh[(size_t)__builtin_amdgcn_readlane(jn, q + 6) * F_OUTT + lane], a6);
    a7 = fmaf(bcastf(av, q + 7), g_Wh[(size_t)__builtin_amdgcn_readlane(jn, q + 7) * F_OUTT + lane], a7);
  }
  for (; q < L; q++)
    a0 = fmaf(bcastf(av, q), g_Wh[(size_t)__builtin_amdgcn_readlane(jn, q) * F_OUTT + lane], a0);
  const float wh2v = ((a0 + a1) + (a2 + a3)) + ((a4 + a5) + (a6 + a7));

  float gx0 = 0.f, gx1 = 0.f, gx2 = 0.f, gx3 = 0.f;
  #pragma unroll
  for (int f = 0; f < 64; f++) {
    const float wf = bcastf(wh2v, f);
    const float4 cv = *(const float4*)(g_WihT + f * 256 + lane * 4);
    gx0 = fmaf(cv.x, wf, gx0);
    gx1 = fmaf(cv.y, wf, gx1);
    gx2 = fmaf(cv.z, wf, gx2);
    gx3 = fmaf(cv.w, wf, gx3);
  }
  gx0 += g_bias[0 * 64 + lane];
  gx1 += g_bias[1 * 64 + lane];
  gx2 += g_bias[2 * 64 + lane];
  gx3 += g_bias[3 * 64 + lane];
  g_GX[(size_t)i * F_OUTT + lane] = make_float4(gx0, gx1, gx2, gx3);
}

// K4-MFMA v12 (r20/r9-proven, REVERTED from v13): 8 rows/block, 512 blocks,
// 2 blocks/CU, gate-cell redistribution, CU-pairing remap.
// r11 post-mortem: v13's wave-private design quadrupled per-SIMD MFMA issue
// (32 MFMAs x ~16cy on ONE SIMD = ~512cy/step, 4x redundant rows) -> 92.6us.
// Lesson: count issue-cycles per pipe per wave, not just chain latency.
// v12 spreads 8 MFMAs across 4 waves/4 SIMDs: 51us proven.
__global__ __launch_bounds__(256, 2) void k_lstm_mfma(
    const void* __restrict__ w_hh, const int* __restrict__ seq,
    void* __restrict__ out)
{
  const bool bf16 = mode_bf16();
  __shared__ __align__(16) unsigned short lds_h[2][16 * 72];  // 4.5 KB dbuf
  __shared__ int lds_idx[8][MAXDEG];                          // 2 KB rev indices
  const int tid = threadIdx.x;
  const int w = tid >> 6, lane = tid & 63;
  const int q = lane >> 4, c = lane & 15;
  const int bid = (int)blockIdx.x;
  const int wb = (bid < 256) ? bid : 767 - bid;   // r20 pairing remap (null but safe)
  const int rb = wb * 8;

  // Zero lds_h (rows 8..15 stay zero forever).
  for (int v = tid; v < 2 * 16 * 72; v += 256) ((unsigned short*)lds_h)[v] = 0;

  // Stage the block's 8 (permuted) rev-index rows into LDS, coalesced.
  for (int v = tid; v < 8 * MAXDEG; v += 256) {
    const int e = v >> 6, t0 = v & (MAXDEG - 1);
    const int row = g_perm[rb + e] & (N_NODES - 1);
    lds_idx[e][t0] = g_rev[row * MAXDEG + t0] & (N_NODES - 1);
  }

  const int Lmax = min(max(seq[g_perm[rb] & (N_NODES - 1)], 0), MAXDEG);

  int rows_c[4];
  #pragma unroll
  for (int r = 0; r < 4; r++) rows_c[r] = min(q * 4 + r, 7);

  int row_own[2], Ls_own[2];
  #pragma unroll
  for (int k = 0; k < 2; k++) {
    row_own[k] = g_perm[rb + 2 * q + k] & (N_NODES - 1);
    Ls_own[k]  = min(max(seq[row_own[k]], 0), MAXDEG);
  }
  const int d_unit = 16 * w + c;
  const int sl = ((lane >> 5) << 4) | c;
  const bool qodd = (q & 1) != 0;

  bf16x8 Bhi[4][2];
  #pragma unroll
  for (int g = 0; g < 4; g++) {
    const int col = 64 * g + d_unit;
    #pragma unroll
    for (int ch = 0; ch < 2; ch++) {
      if (bf16) {
        Bhi[g][ch] = *(const bf16x8*)((const unsigned short*)w_hh + (size_t)col * 64 + ch * 32 + q * 8);
      } else {
        const float* wp = (const float*)w_hh + (size_t)col * 64 + ch * 32 + q * 8;
        float4 va = *(const float4*)wp, vb = *(const float4*)(wp + 4);
        bf16x8 f;
        f[0] = (short)f2bf(va.x); f[1] = (short)f2bf(va.y);
        f[2] = (short)f2bf(va.z); f[3] = (short)f2bf(va.w);
        f[4] = (short)f2bf(vb.x); f[5] = (short)f2bf(vb.y);
        f[6] = (short)f2bf(vb.z); f[7] = (short)f2bf(vb.w);
        Bhi[g][ch] = f;
      }
    }
  }

  __syncthreads();

  float4 gxb[4][4];
  #pragma unroll
  for (int s = 0; s < 4; s++) {
    #pragma unroll
    for (int r = 0; r < 4; r++)
      gxb[s][r] = g_GX[lds_idx[rows_c[r]][s] * F_OUTT + d_unit];
  }
  int idx_cur[4];
  #pragma unroll
  for (int r = 0; r < 4; r++) idx_cur[r] = lds_idx[rows_c[r]][4];

  bf16x8 h0 = zfrag(), h1 = zfrag();
  float cst[2] = {0.f, 0.f}, hst[2] = {0.f, 0.f};
  const int Lr = (Lmax + 3) & ~3;

  for (int t = 0; t < Lr; t += 4) {
    #pragma unroll
    for (int j = 0; j < 4; j++) {
      const int tt = t + j;
      f32x4 acc[4];
      #pragma unroll
      for (int g = 0; g < 4; g++) {
        f32x4 a;
        a[0] = (g==0)?gxb[j][0].x:(g==1)?gxb[j][0].y:(g==2)?gxb[j][0].z:gxb[j][0].w;
        a[1] = (g==0)?gxb[j][1].x:(g==1)?gxb[j][1].y:(g==2)?gxb[j][1].z:gxb[j][1].w;
        a[2] = (g==0)?gxb[j][2].x:(g==1)?gxb[j][2].y:(g==2)?gxb[j][2].z:gxb[j][2].w;
        a[3] = (g==0)?gxb[j][3].x:(g==1)?gxb[j][3].y:(g==2)?gxb[j][3].z:gxb[j][3].w;
        a = MFMA16(h0, Bhi[g][0], a);
        a = MFMA16(h1, Bhi[g][1], a);
        acc[g] = a;
      }
      #pragma unroll
      for (int r = 0; r < 4; r++)
        gxb[j][r] = g_GX[idx_cur[r] * F_OUTT + d_unit];
      {
        const int nt = min(tt + 5, MAXDEG - 1);
        #pragma unroll
        for (int r = 0; r < 4; r++) idx_cur[r] = lds_idx[rows_c[r]][nt];
      }
      float gv[4][2];
      #pragma unroll
      for (int g = 0; g < 4; g++) {
        float t0v = __shfl(acc[g][0], sl);
        float t1v = __shfl(acc[g][1], sl);
        float t2v = __shfl(acc[g][2], sl);
        float t3v = __shfl(acc[g][3], sl);
        gv[g][0] = qodd ? t2v : t0v;
        gv[g][1] = qodd ? t3v : t1v;
      }
      unsigned short* lh = lds_h[j & 1];
      #pragma unroll
      for (int k = 0; k < 2; k++) {
        float ig = sigm(gv[0][k]);
        float fg = sigm(gv[1][k]);
        float gg = tanh_fast(gv[2][k]);
        float og = sigm(gv[3][k]);
        float cn = fg * cst[k] + ig * gg;
        float hn = og * tanh_fast(cn);
        bool live = (tt < Ls_own[k]);
        cst[k] = live ? cn : cst[k];
        hst[k] = live ? hn : hst[k];
        lh[(2 * q + k) * 72 + d_unit] = f2bf(hst[k]);   // RNE bf16
      }
      block_sync_lds();
      {
        const unsigned short* lr_ = lds_h[j & 1] + c * 72;
        h0 = *(const bf16x8*)(lr_ + 8 * q);
        h1 = *(const bf16x8*)(lr_ + 32 + 8 * q);
      }
    }
  }
  #pragma unroll
  for (int k = 0; k < 2; k++) {
    if (bf16) ((__hip_bfloat16*)out)[row_own[k] * HID + d_unit] = __float2bfloat16(hst[k]);
    else      ((float*)out)[row_own[k] * HID + d_unit] = hst[k];
  }
}

extern "C" void kernel_launch(void* const* d_in, const int* in_sizes, int n_in,
                              void* d_out, int out_size, void* d_ws, size_t ws_size,
                              hipStream_t stream) {
  (void)in_sizes; (void)n_in; (void)out_size; (void)d_ws; (void)ws_size;
  const void* h    = d_in[0];
  const void* adj  = d_in[1];
  const int*  seq  = (const int*)d_in[2];
  const void* W    = d_in[3];
  const void* a    = d_in[4];
  const void* w_ih = d_in[5];
  const void* w_hh = d_in[6];
  const void* b_ih = d_in[7];
  const void* b_hh = d_in[8];

  k_detect   <<<64,           256, 0, stream>>>((const unsigned int*)adj);
  k_scan     <<<N_NODES + 1,  256, 0, stream>>>(adj, w_ih, b_ih, b_hh, seq);
  k_wh       <<<N_NODES / 16, 256, 0, stream>>>(h, W, a);
  k_att2     <<<N_NODES,      64,  0, stream>>>();
  k_lstm_mfma<<<N_NODES / 8,  256, 0, stream>>>(w_hh, seq, d_out);
}